// Round 1
// 708.605 us; speedup vs baseline: 1.0074x; 1.0074x over previous
//
#include <hip/hip_runtime.h>

#define D4 512        // 2048 floats = 512 float4 per row
#define K_EDGES 32    // sorted edges per wave-chunk (one 32-lane meta load)

// ---------- sort machinery (counting "sort" by src via bump-alloc) ----------

__global__ void zero_ints(int* __restrict__ p, int n) {
    int i = blockIdx.x * blockDim.x + threadIdx.x;
    if (i < n) p[i] = 0;
}

// cnt layout (64-aligned regions): [0,O1) rel0(ddi) | [O1,O2) rel1(dpi) | [O2,CBp) rel2(ppi)
__global__ void hist3(const int* __restrict__ s0, const int* __restrict__ s1,
                      const int* __restrict__ s2, int E,
                      int* __restrict__ cnt, int O1, int O2) {
    int i = blockIdx.x * blockDim.x + threadIdx.x;
    const int total = 3 * E;
    for (; i < total; i += gridDim.x * blockDim.x) {
        if (i < E)           atomicAdd(&cnt[s0[i]], 1);
        else if (i < 2 * E)  atomicAdd(&cnt[O1 + s1[i - E]], 1);
        else                 atomicAdd(&cnt[O2 + s2[i - 2 * E]], 1);
    }
}

// bump-allocate a contiguous region per non-empty bucket. Region order is
// arbitrary (grouping by src is all the score kernel needs), so no global
// prefix scan: wave-level shfl scan + ONE atomic per wave on a relation cursor.
// Regions are 64-aligned so each wave sees exactly one relation.
__global__ void alloc3(const int* __restrict__ cnt, int* __restrict__ base,
                       int* __restrict__ cursors, int O1, int O2, int CBp) {
    int i = blockIdx.x * blockDim.x + threadIdx.x;
    if (i >= CBp) return;                  // whole waves only (CBp % 64 == 0)
    const int lane = threadIdx.x & 63;
    const int rel = (i >= O2) ? 2 : (i >= O1) ? 1 : 0;   // wave-uniform
    int c = cnt[i];
    int x = c;                              // inclusive scan across the wave
#pragma unroll
    for (int d = 1; d < 64; d <<= 1) {
        int y = __shfl_up(x, d, 64);
        if (lane >= d) x += y;
    }
    int tot = __shfl(x, 63);
    int wb = 0;
    if (lane == 63) wb = atomicAdd(&cursors[rel], tot);
    wb = __shfl(wb, 63);
    base[i] = wb + x - c;                   // exclusive position within relation
}

// scatter edge ids AND packed (src,dst) into src-grouped order
__global__ void scatter3(const int* __restrict__ s0, const int* __restrict__ d0_,
                         const int* __restrict__ s1, const int* __restrict__ d1_,
                         const int* __restrict__ s2, const int* __restrict__ d2_,
                         int E, int* __restrict__ base, int O1, int O2,
                         int* __restrict__ sorted, int* __restrict__ sd) {
    int i = blockIdx.x * blockDim.x + threadIdx.x;
    const int total = 3 * E;
    for (; i < total; i += gridDim.x * blockDim.x) {
        if (i < E) {
            int s = s0[i], d = d0_[i];
            int p = atomicAdd(&base[s], 1);
            sorted[p] = i; sd[p] = (s << 16) | d;
        } else if (i < 2 * E) {
            int k = i - E; int s = s1[k], d = d1_[k];
            int p = atomicAdd(&base[O1 + s], 1);
            sorted[E + p] = k; sd[E + p] = (s << 16) | d;
        } else {
            int k = i - 2 * E; int s = s2[k], d = d2_[k];
            int p = atomicAdd(&base[O2 + s], 1);
            sorted[2 * E + p] = k; sd[2 * E + p] = (s << 16) | d;
        }
    }
}

// ---------- scoring over src-grouped edges ----------
// Per chunk: one coalesced 32-lane load of (edge-id, packed src|dst) metadata,
// distributed via shfl (removes the dependent scalar-load chain from the
// critical path). Tail rows double-buffered tA/tB so edge i+1's 8 loads are
// in flight during edge i's FMA+reduce. head*rel cached in 32 VGPRs per
// same-src run; rel re-read from L1 at run switches (frees 32 VGPRs).
__global__ __launch_bounds__(256, 4) void score_sorted(
    const float4* __restrict__ xdrug, const float4* __restrict__ xprot,
    const float4* __restrict__ rddi,  const float4* __restrict__ rdpi,
    const int* __restrict__ sorted, const int* __restrict__ sd,
    int* __restrict__ queue, float* __restrict__ out, int E)
{
    const int lane = threadIdx.x & 63;
    const int wpb = blockDim.x >> 6;
    const int wid = blockIdx.x * wpb + (threadIdx.x >> 6);
    const int nw = gridDim.x * wpb;
    const int cpr = (E + K_EDGES - 1) / K_EDGES;
    const int total_chunks = 3 * cpr;

    int c = wid;
    while (c < total_chunks) {
        const int r = (c >= 2 * cpr) ? 2 : (c >= cpr) ? 1 : 0;
        const int ci = c - r * cpr;
        const int e_lo = ci * K_EDGES;
        const int n = min(K_EDGES, E - e_lo);

        const float4 *xs, *xd, *rel;
        if (r == 0)      { xs = xdrug; xd = xdrug; rel = rddi; }
        else if (r == 1) { xs = xdrug; xd = xprot; rel = rdpi; }
        else             { xs = xprot; xd = xprot; rel = rdpi; }
        const int* sl  = sorted + (size_t)r * E + e_lo;
        const int* sdl = sd     + (size_t)r * E + e_lo;
        float* o = out + (size_t)r * E;

        int eL = 0, sdL = 0;
        if (lane < n) { eL = sl[lane]; sdL = sdl[lane]; }

        float4 hr[8], tA[8], tB[8];
        int cur = -1;

        {   // prologue: tail row for edge 0
            int sd0 = __shfl(sdL, 0);
            const float4* tp = xd + (size_t)(sd0 & 0xffff) * D4;
#pragma unroll
            for (int j = 0; j < 8; ++j) tA[j] = tp[j * 64 + lane];
        }

        for (int i = 0; i < n; i += 2) {
            // prefetch edge i+1 tail into tB (issues before edge i's waits)
            if (i + 1 < n) {
                int sdn = __shfl(sdL, i + 1);
                const float4* tq = xd + (size_t)(sdn & 0xffff) * D4;
#pragma unroll
                for (int j = 0; j < 8; ++j) tB[j] = tq[j * 64 + lane];
            }
            {   // compute edge i from tA
                int sdi = __shfl(sdL, i);
                int s = sdi >> 16;
                if (s != cur) {               // wave-uniform branch
                    cur = s;
                    const float4* hp = xs + (size_t)s * D4;
#pragma unroll
                    for (int j = 0; j < 8; ++j) {
                        float4 h = hp[j * 64 + lane], rv = rel[j * 64 + lane];
                        hr[j].x = h.x * rv.x; hr[j].y = h.y * rv.y;
                        hr[j].z = h.z * rv.z; hr[j].w = h.w * rv.w;
                    }
                }
                float acc = 0.f;
#pragma unroll
                for (int j = 0; j < 8; ++j) {
                    acc = fmaf(hr[j].x, tA[j].x, acc);
                    acc = fmaf(hr[j].y, tA[j].y, acc);
                    acc = fmaf(hr[j].z, tA[j].z, acc);
                    acc = fmaf(hr[j].w, tA[j].w, acc);
                }
#pragma unroll
                for (int off = 32; off; off >>= 1) acc += __shfl_down(acc, off, 64);
                int e = __shfl(eL, i);
                if (lane == 0) o[e] = fminf(fmaxf(acc, 0.f), 1.f);
            }
            if (i + 1 >= n) break;
            // prefetch edge i+2 tail into tA
            if (i + 2 < n) {
                int sdn = __shfl(sdL, i + 2);
                const float4* tq = xd + (size_t)(sdn & 0xffff) * D4;
#pragma unroll
                for (int j = 0; j < 8; ++j) tA[j] = tq[j * 64 + lane];
            }
            {   // compute edge i+1 from tB
                int sdi = __shfl(sdL, i + 1);
                int s = sdi >> 16;
                if (s != cur) {
                    cur = s;
                    const float4* hp = xs + (size_t)s * D4;
#pragma unroll
                    for (int j = 0; j < 8; ++j) {
                        float4 h = hp[j * 64 + lane], rv = rel[j * 64 + lane];
                        hr[j].x = h.x * rv.x; hr[j].y = h.y * rv.y;
                        hr[j].z = h.z * rv.z; hr[j].w = h.w * rv.w;
                    }
                }
                float acc = 0.f;
#pragma unroll
                for (int j = 0; j < 8; ++j) {
                    acc = fmaf(hr[j].x, tB[j].x, acc);
                    acc = fmaf(hr[j].y, tB[j].y, acc);
                    acc = fmaf(hr[j].z, tB[j].z, acc);
                    acc = fmaf(hr[j].w, tB[j].w, acc);
                }
#pragma unroll
                for (int off = 32; off; off >>= 1) acc += __shfl_down(acc, off, 64);
                int e = __shfl(eL, i + 1);
                if (lane == 0) o[e] = fminf(fmaxf(acc, 0.f), 1.f);
            }
        }

        // dynamic work queue: perfect load balance at K=32
        int nc = 0;
        if (lane == 0) nc = atomicAdd(queue, 1);
        c = nw + __shfl(nc, 0);
    }
}

// ---------- fallback (direct kernel) if ws too small ----------
__global__ __launch_bounds__(256) void edge_score_all(
    const float4* __restrict__ xdrug, const float4* __restrict__ xprot,
    const float4* __restrict__ rddi,  const float4* __restrict__ rdpi,
    const int* __restrict__ ddi_src, const int* __restrict__ ddi_dst,
    const int* __restrict__ dpi_src, const int* __restrict__ dpi_dst,
    const int* __restrict__ ppi_src, const int* __restrict__ ppi_dst,
    float* __restrict__ out, int E)
{
    __shared__ float4 srel[2][D4];
    for (int i = threadIdx.x; i < D4; i += blockDim.x) {
        srel[0][i] = rddi[i];
        srel[1][i] = rdpi[i];
    }
    __syncthreads();
    const int lane = threadIdx.x & 63;
    const int wpb = blockDim.x >> 6;
    int wid = blockIdx.x * wpb + (threadIdx.x >> 6);
    const int nw = gridDim.x * wpb;
    const int total = 3 * E;
    for (int e = wid; e < total; e += nw) {
        const float4 *hp, *tp;
        int sel;
        if (e < E)          { hp = xdrug + (size_t)ddi_src[e] * D4; tp = xdrug + (size_t)ddi_dst[e] * D4; sel = 0; }
        else if (e < 2 * E) { int k = e - E;     hp = xdrug + (size_t)dpi_src[k] * D4; tp = xprot + (size_t)dpi_dst[k] * D4; sel = 1; }
        else                { int k = e - 2 * E; hp = xprot + (size_t)ppi_src[k] * D4; tp = xprot + (size_t)ppi_dst[k] * D4; sel = 1; }
        float acc = 0.f;
#pragma unroll
        for (int j = 0; j < 8; ++j) {
            const int idx = j * 64 + lane;
            float4 h = hp[idx], t = tp[idx], rr = srel[sel][idx];
            acc = fmaf(h.x * rr.x, t.x, acc);
            acc = fmaf(h.y * rr.y, t.y, acc);
            acc = fmaf(h.z * rr.z, t.z, acc);
            acc = fmaf(h.w * rr.w, t.w, acc);
        }
#pragma unroll
        for (int off = 32; off; off >>= 1) acc += __shfl_down(acc, off, 64);
        if (lane == 0) out[e] = fminf(fmaxf(acc, 0.f), 1.f);
    }
}

extern "C" void kernel_launch(void* const* d_in, const int* in_sizes, int n_in,
                              void* d_out, int out_size, void* d_ws, size_t ws_size,
                              hipStream_t stream) {
    const float* x_drug    = (const float*)d_in[0];
    const float* x_protein = (const float*)d_in[1];
    const float* rel_ddi   = (const float*)d_in[2];
    const float* rel_dpi   = (const float*)d_in[3];
    const int* ddi_src = (const int*)d_in[4];
    const int* ddi_dst = (const int*)d_in[5];
    const int* dpi_src = (const int*)d_in[6];
    const int* dpi_dst = (const int*)d_in[7];
    const int* ppi_src = (const int*)d_in[8];
    const int* ppi_dst = (const int*)d_in[9];

    const int D  = in_sizes[2];              // 2048
    const int nd = in_sizes[0] / D;          // N_DRUG
    const int np = in_sizes[1] / D;          // N_PROT
    const int E  = in_sizes[4];              // edges per relation
    float* out = (float*)d_out;

    const int ndp = ((nd + 63) / 64) * 64;   // 64-aligned region sizes
    const int npp = ((np + 63) / 64) * 64;
    const int O1  = ndp;                     // region offsets
    const int O2  = ndp + ndp;
    const int CBp = O2 + npp;

    const size_t need = (size_t)(2 * CBp + 8 + 6 * E) * sizeof(int);

    if (ws_size < need) {                    // fallback: direct kernel
        edge_score_all<<<2048, 256, 0, stream>>>(
            (const float4*)x_drug, (const float4*)x_protein,
            (const float4*)rel_ddi, (const float4*)rel_dpi,
            ddi_src, ddi_dst, dpi_src, dpi_dst, ppi_src, ppi_dst, out, E);
        return;
    }

    int* cnt    = (int*)d_ws;                // CBp ints
    int* aux    = cnt + CBp;                 // 8 ints: cursors[3], queue at [3]
    int* base   = aux + 8;                   // CBp ints (becomes cursor)
    int* sorted = base + CBp;                // 3E ints  (edge ids, grouped by src)
    int* sd     = sorted + 3 * E;            // 3E ints  ((src<<16)|dst, same order)

    zero_ints<<<(CBp + 8 + 255) / 256, 256, 0, stream>>>(cnt, CBp + 8);
    hist3<<<1024, 256, 0, stream>>>(ddi_src, dpi_src, ppi_src, E, cnt, O1, O2);
    alloc3<<<(CBp + 255) / 256, 256, 0, stream>>>(cnt, base, aux, O1, O2, CBp);
    scatter3<<<1024, 256, 0, stream>>>(ddi_src, ddi_dst, dpi_src, dpi_dst,
                                       ppi_src, ppi_dst, E, base, O1, O2, sorted, sd);

    score_sorted<<<1024, 256, 0, stream>>>(
        (const float4*)x_drug, (const float4*)x_protein,
        (const float4*)rel_ddi, (const float4*)rel_dpi,
        sorted, sd, aux + 3, out, E);
}